// Round 10
// baseline (540.113 us; speedup 1.0000x reference)
//
#include <hip/hip_runtime.h>
#include <hip/hip_fp16.h>
#include <math.h>

static constexpr float PI2Q = 1.57079632679489662f; // 2*pi*Q, Q=0.25
#define NRANGE 8
#define NS2 16       // src-groups per range (key low bits)
#define GSH2 13      // src-group shift: 8192 nodes/group -> <=13 groups for N=100K
#define NKEY (NRANGE * NS2)
#define MAXRNG 13056 // LDS histogram capacity (ints); ceil(N/8) must be <= this

__device__ __forceinline__ float2 h2f_bits(int b) {
  __half2 h = *reinterpret_cast<__half2*>(&b);
  return __half22float2(h);
}
__device__ __forceinline__ int f2h_bits(float a, float b) {
  __half2 h = __floats2half2_rn(a, b);
  return *reinterpret_cast<int*>(&h);
}
__device__ __forceinline__ int grp_of(int s) {
  int g = s >> GSH2;
  return (g > NS2 - 1) ? (NS2 - 1) : g;
}

// ---------------- head folding: w_eff[k] = sum_j Wc[j,k]*Wl[j]; w_eff[32] = bc@Wl + bl
__global__ void k_weff(const float* __restrict__ Wc, const float* __restrict__ bc,
                       const float* __restrict__ Wl, const float* __restrict__ bl,
                       float* __restrict__ weff) {
  int k = threadIdx.x;
  if (k < 32) {
    float s = 0.f;
    #pragma unroll
    for (int j = 0; j < 32; ++j) s += Wc[j * 32 + k] * Wl[j];
    weff[k] = s;
  } else if (k == 32) {
    float s = 0.f;
    for (int j = 0; j < 32; ++j) s += bc[j] * Wl[j];
    weff[32] = s + bl[0];
  }
}

// ---------------- embedding + layer-1 dense premultiplies (f32 PQ + fp16 PQh)
__global__ __launch_bounds__(256) void k_embed(
    const int* __restrict__ x, const float* __restrict__ btab,
    const float* __restrict__ gtab, const float* __restrict__ stab,
    const float* __restrict__ W1, const float* __restrict__ b1,
    float* __restrict__ PQ, __half2* __restrict__ PQh, float* __restrict__ o0, int n) {
  __shared__ float sm[3184];
  int tid = threadIdx.x;
  for (int t = tid; t < 1536; t += 256) sm[t] = W1[t];
  if (tid < 16) sm[1536 + tid] = b1[tid];
  for (int t = tid; t < 128; t += 256) sm[1552 + t] = btab[t];
  for (int t = tid; t < 64; t += 256) sm[1680 + t] = gtab[t];
  for (int t = tid; t < 1440; t += 256) sm[1744 + t] = stab[t];
  __syncthreads();
  int i = blockIdx.x * 256 + tid;
  if (i >= n) return;
  int xr[20];
  #pragma unroll
  for (int j = 0; j < 20; ++j) xr[j] = x[i * 20 + j];
  int bi = 0;
  #pragma unroll
  for (int j = 3; j >= 0; --j) if (xr[j] == 1) bi = j;
  int g = xr[4];
  float h[32];
  #pragma unroll
  for (int f = 0; f < 32; ++f) {
    float s = 0.f;
    #pragma unroll
    for (int j = 0; j < 15; ++j) s += sm[1744 + j * 96 + xr[5 + j] * 32 + f];
    h[f] = (sm[1552 + bi * 32 + f] + sm[1680 + g * 32 + f] + s * (1.f / 15.f)) * (1.f / 3.f);
  }
  #pragma unroll
  for (int f = 0; f < 16; ++f) {
    float o = sm[1536 + f], p = 0.f, q = 0.f;
    #pragma unroll
    for (int k = 0; k < 32; ++k) {
      float hk = h[k];
      o = fmaf(hk, sm[k * 16 + f], o);
      p = fmaf(hk, sm[512 + k * 16 + f], p);
      q = fmaf(hk, sm[1024 + k * 16 + f], q);
    }
    o0[i * 16 + f] = o;
    PQ[i * 32 + 2 * f] = p;
    PQ[i * 32 + 2 * f + 1] = q;
    PQh[(size_t)i * 16 + f] = __floats2half2_rn(p, q);
  }
}

// ---------------- 128-key histogram: key = (dst_range<<4) | src_group
__global__ __launch_bounds__(256) void k_rhist(const int* __restrict__ ei, int* __restrict__ rcnt,
                                               int rng, int E_) {
  __shared__ int h[NKEY * 8];
  int tid = threadIdx.x;
  for (int t = tid; t < NKEY * 8; t += 256) h[t] = 0;
  __syncthreads();
  int slot = tid & 7;
  int stride = gridDim.x * 256;
  for (int e = blockIdx.x * 256 + tid; e < E_; e += stride) {
    int s = ei[e], d = ei[E_ + e];
    int keyA = ((d / rng) << 4) | grp_of(s);
    int keyB = ((s / rng) << 4) | grp_of(d);
    atomicAdd(&h[keyA * 8 + slot], 1);
    atomicAdd(&h[keyB * 8 + slot], 1);
  }
  __syncthreads();
  for (int t = tid; t < NKEY; t += 256) {
    int sum = 0;
    #pragma unroll
    for (int j = 0; j < 8; ++j) sum += h[t * 8 + j];
    if (sum) atomicAdd(&rcnt[t], sum);
  }
}

// ---------------- key bases + cursor init
__global__ void k_rbase(const int* __restrict__ rcnt, int* __restrict__ rbase, int* __restrict__ rcur) {
  if (threadIdx.x == 0) {
    int run = 0;
    for (int r = 0; r < NKEY; ++r) { rbase[r] = run; rcur[r] = run; run += rcnt[r]; }
    rbase[NKEY] = run;
  }
}

// ---------------- bucket stubs by (range, src_group); block-level reservation
__global__ __launch_bounds__(256) void k_bucket(const int* __restrict__ ei, const float* __restrict__ ew,
                                                int* __restrict__ rcur, int* __restrict__ brow,
                                                int2* __restrict__ bsw, int rng, int E_) {
  __shared__ int lcnt[NKEY];
  __shared__ int gbase[NKEY];
  int tid = threadIdx.x;
  if (tid < NKEY) lcnt[tid] = 0;
  __syncthreads();
  int e0 = blockIdx.x * 1024;
  int s[4], d[4], wb[4], kA[4], kB[4], la[4], lb[4];
  #pragma unroll
  for (int j = 0; j < 4; ++j) {
    int e = e0 + j * 256 + tid;
    if (e < E_) {
      s[j] = ei[e]; d[j] = ei[E_ + e]; wb[j] = __float_as_int(ew[e]);
      kA[j] = ((d[j] / rng) << 4) | grp_of(s[j]);
      kB[j] = ((s[j] / rng) << 4) | grp_of(d[j]);
      la[j] = atomicAdd(&lcnt[kA[j]], 1);
      lb[j] = atomicAdd(&lcnt[kB[j]], 1);
    } else {
      kA[j] = -1; kB[j] = -1; s[j] = 0; d[j] = 0; wb[j] = 0; la[j] = 0; lb[j] = 0;
    }
  }
  __syncthreads();
  if (tid < NKEY) gbase[tid] = lcnt[tid] ? atomicAdd(&rcur[tid], lcnt[tid]) : 0;
  __syncthreads();
  #pragma unroll
  for (int j = 0; j < 4; ++j) {
    if (kA[j] >= 0) {
      int pA = gbase[kA[j]] + la[j];
      brow[pA] = d[j];
      bsw[pA] = make_int2(s[j], wb[j]);                    // theta = +
      int pB = gbase[kB[j]] + lb[j];
      brow[pB] = s[j];
      bsw[pB] = make_int2(d[j] | (int)0x80000000, wb[j]);  // theta = -
    }
  }
}

// ---------------- per-(range,group) LDS histogram; blockIdx&7 = range -> XCD pinning
__global__ __launch_bounds__(1024) void k_hist2(const int* __restrict__ brow, const int* __restrict__ rbase,
                                                int* __restrict__ Hg, int rng) {
  __shared__ int hist[MAXRNG];
  int r = blockIdx.x & (NRANGE - 1);
  int st = blockIdx.x >> 3;
  int key = (r << 4) | st;
  int tid = threadIdx.x;
  for (int t = tid; t < rng; t += 1024) hist[t] = 0;
  __syncthreads();
  int k0 = rbase[key], k1 = rbase[key + 1];
  int base = r * rng;
  for (int k = k0 + tid; k < k1; k += 1024)
    atomicAdd(&hist[brow[k] - base], 1);
  __syncthreads();
  int* plane = Hg + (size_t)(r * NS2 + st) * rng;
  for (int t = tid; t < rng; t += 1024) plane[t] = hist[t];
}

// ---------------- scanH: per node, exclusive prefix across the NS2 groups; total -> cnt
__global__ __launch_bounds__(512) void k_scanH(int* __restrict__ Hg, int* __restrict__ cnt,
                                               int rng, int n) {
  int v = blockIdx.x * 512 + threadIdx.x;
  if (v >= n) return;
  int r = v / rng;
  int vloc = v - r * rng;
  int run = 0;
  size_t idx = (size_t)(r * NS2) * rng + vloc;
  #pragma unroll 4
  for (int s = 0; s < NS2; ++s) {
    int t = Hg[idx];
    Hg[idx] = run;
    run += t;
    idx += rng;
  }
  cnt[v] = run;
}

// ---------------- 3-kernel exclusive scan
__global__ __launch_bounds__(1024) void k_scan_a(const int* __restrict__ cnt, int* __restrict__ rowp,
                                                 int* __restrict__ bsum, int n) {
  __shared__ int sh[1024];
  int tid = threadIdx.x;
  int idx = blockIdx.x * 1024 + tid;
  int v = (idx < n) ? cnt[idx] : 0;
  sh[tid] = v;
  __syncthreads();
  for (int offd = 1; offd < 1024; offd <<= 1) {
    int t = (tid >= offd) ? sh[tid - offd] : 0;
    __syncthreads();
    sh[tid] += t;
    __syncthreads();
  }
  if (idx < n) rowp[idx] = sh[tid] - v;
  if (tid == 1023) bsum[blockIdx.x] = sh[1023];
}

__global__ __launch_bounds__(128) void k_scan_b(int* __restrict__ bsum, int nb,
                                                int* __restrict__ rowp, int n) {
  __shared__ int sh[128];
  int tid = threadIdx.x;
  int v = (tid < nb) ? bsum[tid] : 0;
  sh[tid] = v;
  __syncthreads();
  for (int offd = 1; offd < 128; offd <<= 1) {
    int t = (tid >= offd) ? sh[tid - offd] : 0;
    __syncthreads();
    sh[tid] += t;
    __syncthreads();
  }
  if (tid < nb) bsum[tid] = sh[tid] - v;
  if (tid == 127) rowp[n] = sh[127];
}

__global__ __launch_bounds__(1024) void k_scan_c(int* __restrict__ rowp, const int* __restrict__ bsum, int n) {
  int idx = blockIdx.x * 1024 + threadIdx.x;
  if (idx < n && blockIdx.x > 0) rowp[idx] += bsum[blockIdx.x];
}

// ---------------- placement; rows emerge src-group-sorted; blockIdx&7 = range -> XCD pinning
__global__ __launch_bounds__(1024) void k_place2(const int* __restrict__ brow, const int2* __restrict__ bsw,
                                                 const int* __restrict__ rbase, const int* __restrict__ rowp,
                                                 const int* __restrict__ Hoff, int2* __restrict__ recs,
                                                 int rng) {
  __shared__ int hist[MAXRNG];
  int r = blockIdx.x & (NRANGE - 1);
  int st = blockIdx.x >> 3;
  int key = (r << 4) | st;
  int tid = threadIdx.x;
  for (int t = tid; t < rng; t += 1024) hist[t] = 0;
  __syncthreads();
  int k0 = rbase[key], k1 = rbase[key + 1];
  int base = r * rng;
  const int* plane = Hoff + (size_t)(r * NS2 + st) * rng;
  for (int k = k0 + tid; k < k1; k += 1024) {
    int row = brow[k];
    int rowloc = row - base;
    int lr = atomicAdd(&hist[rowloc], 1);
    recs[rowp[row] + plane[rowloc] + lr] = bsw[k];
  }
}

// ---------------- weighted degree -> dinv
__global__ __launch_bounds__(256) void k_rowdeg(const int* __restrict__ rowp, const int2* __restrict__ recs,
                                                float* __restrict__ dinv, int n) {
  int wid = (blockIdx.x * 256 + threadIdx.x) >> 6;
  if (wid >= n) return;
  int lane = threadIdx.x & 63;
  int rs = rowp[wid], re = rowp[wid + 1];
  float sum = 0.f;
  for (int k = rs + lane; k < re; k += 64) sum += __int_as_float(recs[k].y);
  sum += __shfl_xor(sum, 1); sum += __shfl_xor(sum, 2);
  sum += __shfl_xor(sum, 4); sum += __shfl_xor(sum, 8);
  sum += __shfl_xor(sum, 16); sum += __shfl_xor(sum, 32);
  if (lane == 0) {
    float dg = 0.5f * sum;
    dinv[wid] = (dg > 0.f) ? rsqrtf(dg) : 0.f;
  }
}

// ---------------- per-stub normalization; packs half2(ar, ai_signed) into recs[k].y
__global__ __launch_bounds__(256) void k_norm(const int* __restrict__ rowp, int2* __restrict__ recs,
                                              const float* __restrict__ dinv, int n) {
  int wid = (blockIdx.x * 256 + threadIdx.x) >> 6;
  if (wid >= n) return;
  int lane = threadIdx.x & 63;
  float di = dinv[wid];
  int rs = rowp[wid], re = rowp[wid + 1];
  for (int k = rs + lane; k < re; k += 64) {
    int2 r = recs[k];
    int s = r.x & 0x7fffffff;
    float w = __int_as_float(r.y);
    float nrm = di * 0.5f * w * dinv[s];
    float sn, cs;
    sincosf(PI2Q * w, &sn, &cs);
    float ar = -nrm * cs;
    float ai = (r.x < 0) ? nrm * sn : -nrm * sn;
    recs[k].y = f2h_bits(ar, ai);
  }
}

// ---------------- layer-1 hop 1 (xr==xi symmetry): stub-quad layout (16 stubs x 4 lanes)
__global__ __launch_bounds__(256, 8) void k_hop_sym(
    const int* __restrict__ rowp, const int2* __restrict__ recs,
    const __half2* __restrict__ PQh, __half2* __restrict__ Uh, float* __restrict__ AB, int n) {
  int wid = (blockIdx.x * 256 + threadIdx.x) >> 6;
  if (wid >= n) return;
  int lane = threadIdx.x & 63;
  int fq = lane & 3, su = lane >> 2;
  int rs = rowp[wid], rend = rowp[wid + 1];
  float aA[4] = {0.f, 0.f, 0.f, 0.f}, aB[4] = {0.f, 0.f, 0.f, 0.f};
  float aC[4] = {0.f, 0.f, 0.f, 0.f}, aD[4] = {0.f, 0.f, 0.f, 0.f};
  const long long* rq = reinterpret_cast<const long long*>(recs);
  const int4* Pq = reinterpret_cast<const int4*>(PQh);
  for (int k = rs + su; k < rend; k += 16) {
    long long r0 = __builtin_nontemporal_load(rq + k);
    int s = ((int)r0) & 0x7fffffff;
    float2 a = h2f_bits((int)(r0 >> 32));
    float wm = a.x - a.y, wp = a.x + a.y;
    int4 v = Pq[(size_t)s * 4 + fq];
    float2 x0 = h2f_bits(v.x), x1 = h2f_bits(v.y), x2 = h2f_bits(v.z), x3 = h2f_bits(v.w);
    aA[0] = fmaf(wm, x0.x, aA[0]); aB[0] = fmaf(wp, x0.x, aB[0]);
    aC[0] = fmaf(wm, x0.y, aC[0]); aD[0] = fmaf(wp, x0.y, aD[0]);
    aA[1] = fmaf(wm, x1.x, aA[1]); aB[1] = fmaf(wp, x1.x, aB[1]);
    aC[1] = fmaf(wm, x1.y, aC[1]); aD[1] = fmaf(wp, x1.y, aD[1]);
    aA[2] = fmaf(wm, x2.x, aA[2]); aB[2] = fmaf(wp, x2.x, aB[2]);
    aC[2] = fmaf(wm, x2.y, aC[2]); aD[2] = fmaf(wp, x2.y, aD[2]);
    aA[3] = fmaf(wm, x3.x, aA[3]); aB[3] = fmaf(wp, x3.x, aB[3]);
    aC[3] = fmaf(wm, x3.y, aC[3]); aD[3] = fmaf(wp, x3.y, aD[3]);
  }
  #pragma unroll
  for (int j = 0; j < 4; ++j) {
    aA[j] += __shfl_xor(aA[j], 4); aA[j] += __shfl_xor(aA[j], 8);
    aA[j] += __shfl_xor(aA[j], 16); aA[j] += __shfl_xor(aA[j], 32);
    aB[j] += __shfl_xor(aB[j], 4); aB[j] += __shfl_xor(aB[j], 8);
    aB[j] += __shfl_xor(aB[j], 16); aB[j] += __shfl_xor(aB[j], 32);
    aC[j] += __shfl_xor(aC[j], 4); aC[j] += __shfl_xor(aC[j], 8);
    aC[j] += __shfl_xor(aC[j], 16); aC[j] += __shfl_xor(aC[j], 32);
    aD[j] += __shfl_xor(aD[j], 4); aD[j] += __shfl_xor(aD[j], 8);
    aD[j] += __shfl_xor(aD[j], 16); aD[j] += __shfl_xor(aD[j], 32);
  }
  if (lane < 4) {
    *reinterpret_cast<float4*>(AB + wid * 32 + 8 * fq) = make_float4(aA[0], aB[0], aA[1], aB[1]);
    *reinterpret_cast<float4*>(AB + wid * 32 + 8 * fq + 4) = make_float4(aA[2], aB[2], aA[3], aB[3]);
    int4 hv;
    hv.x = f2h_bits(aC[0], aD[0]); hv.y = f2h_bits(aC[1], aD[1]);
    hv.z = f2h_bits(aC[2], aD[2]); hv.w = f2h_bits(aC[3], aD[3]);
    *reinterpret_cast<int4*>(Uh + (size_t)wid * 16 + 4 * fq) = hv;
  }
}

// ---------------- full complex hop, stub-quad layout. MODE 0: f32 out; 1: layer-1 epilogue; 2: head
template <int MODE>
__global__ __launch_bounds__(256, 8) void k_hop_full(
    const int* __restrict__ rowp, const int2* __restrict__ recs,
    const __half2* __restrict__ Xh, float* __restrict__ Y, __half2* __restrict__ Yh,
    const float* __restrict__ o0, const float* __restrict__ AB, const float* __restrict__ PQ,
    const float* __restrict__ D, const float* __restrict__ weff, int n) {
  int wid = (blockIdx.x * 256 + threadIdx.x) >> 6;
  if (wid >= n) return;
  int lane = threadIdx.x & 63;
  int fq = lane & 3, su = lane >> 2;
  int rs = rowp[wid], rend = rowp[wid + 1];
  float aR[4] = {0.f, 0.f, 0.f, 0.f}, aI[4] = {0.f, 0.f, 0.f, 0.f};
  const long long* rq = reinterpret_cast<const long long*>(recs);
  const int4* Xq = reinterpret_cast<const int4*>(Xh);
  for (int k = rs + su; k < rend; k += 16) {
    long long r0 = __builtin_nontemporal_load(rq + k);
    int s = ((int)r0) & 0x7fffffff;
    float2 a = h2f_bits((int)(r0 >> 32));
    int4 v = Xq[(size_t)s * 4 + fq];
    float2 x0 = h2f_bits(v.x), x1 = h2f_bits(v.y), x2 = h2f_bits(v.z), x3 = h2f_bits(v.w);
    aR[0] = fmaf(a.x, x0.x, aR[0]); aR[0] = fmaf(-a.y, x0.y, aR[0]);
    aI[0] = fmaf(a.x, x0.y, aI[0]); aI[0] = fmaf(a.y, x0.x, aI[0]);
    aR[1] = fmaf(a.x, x1.x, aR[1]); aR[1] = fmaf(-a.y, x1.y, aR[1]);
    aI[1] = fmaf(a.x, x1.y, aI[1]); aI[1] = fmaf(a.y, x1.x, aI[1]);
    aR[2] = fmaf(a.x, x2.x, aR[2]); aR[2] = fmaf(-a.y, x2.y, aR[2]);
    aI[2] = fmaf(a.x, x2.y, aI[2]); aI[2] = fmaf(a.y, x2.x, aI[2]);
    aR[3] = fmaf(a.x, x3.x, aR[3]); aR[3] = fmaf(-a.y, x3.y, aR[3]);
    aI[3] = fmaf(a.x, x3.y, aI[3]); aI[3] = fmaf(a.y, x3.x, aI[3]);
  }
  #pragma unroll
  for (int j = 0; j < 4; ++j) {
    aR[j] += __shfl_xor(aR[j], 4); aR[j] += __shfl_xor(aR[j], 8);
    aR[j] += __shfl_xor(aR[j], 16); aR[j] += __shfl_xor(aR[j], 32);
    aI[j] += __shfl_xor(aI[j], 4); aI[j] += __shfl_xor(aI[j], 8);
    aI[j] += __shfl_xor(aI[j], 16); aI[j] += __shfl_xor(aI[j], 32);
  }
  if (MODE == 2) {
    float c = 0.f;
    if (lane < 4) {
      float4 d0 = *reinterpret_cast<const float4*>(D + wid * 32 + 8 * fq);
      float4 d1 = *reinterpret_cast<const float4*>(D + wid * 32 + 8 * fq + 4);
      float4 w0 = *reinterpret_cast<const float4*>(weff + 4 * fq);
      float4 w1 = *reinterpret_cast<const float4*>(weff + 16 + 4 * fq);
      c  = (d0.x + 2.f * aR[0]) * w0.x + (d0.y + 2.f * aI[0]) * w1.x;
      c += (d0.z + 2.f * aR[1]) * w0.y + (d0.w + 2.f * aI[1]) * w1.y;
      c += (d1.x + 2.f * aR[2]) * w0.z + (d1.y + 2.f * aI[2]) * w1.z;
      c += (d1.z + 2.f * aR[3]) * w0.w + (d1.w + 2.f * aI[3]) * w1.w;
    }
    c += __shfl_xor(c, 1); c += __shfl_xor(c, 2);
    if (lane == 0) Y[wid] = c + weff[32];
  } else if (lane < 4) {
    if (MODE == 0) {
      *reinterpret_cast<float4*>(Y + wid * 32 + 8 * fq) = make_float4(aR[0], aI[0], aR[1], aI[1]);
      *reinterpret_cast<float4*>(Y + wid * 32 + 8 * fq + 4) = make_float4(aR[2], aI[2], aR[3], aI[3]);
    } else {
      float4 o = *reinterpret_cast<const float4*>(o0 + wid * 16 + 4 * fq);
      float4 ab0 = *reinterpret_cast<const float4*>(AB + wid * 32 + 8 * fq);
      float4 ab1 = *reinterpret_cast<const float4*>(AB + wid * 32 + 8 * fq + 4);
      float4 pq0 = *reinterpret_cast<const float4*>(PQ + wid * 32 + 8 * fq);
      float4 pq1 = *reinterpret_cast<const float4*>(PQ + wid * 32 + 8 * fq + 4);
      float zr0 = o.x + ab0.x + 2.f * aR[0] - pq0.y;
      float zi0 = o.x + ab0.y + 2.f * aI[0] - pq0.y;
      float zr1 = o.y + ab0.z + 2.f * aR[1] - pq0.w;
      float zi1 = o.y + ab0.w + 2.f * aI[1] - pq0.w;
      float zr2 = o.z + ab1.x + 2.f * aR[2] - pq1.y;
      float zi2 = o.z + ab1.y + 2.f * aI[2] - pq1.y;
      float zr3 = o.w + ab1.z + 2.f * aR[3] - pq1.w;
      float zi3 = o.w + ab1.w + 2.f * aI[3] - pq1.w;
      *reinterpret_cast<float4*>(Y + wid * 32 + 8 * fq) = make_float4(zr0, zi0, zr1, zi1);
      *reinterpret_cast<float4*>(Y + wid * 32 + 8 * fq + 4) = make_float4(zr2, zi2, zr3, zi3);
      int4 hv;
      hv.x = f2h_bits(zr0, zi0); hv.y = f2h_bits(zr1, zi1);
      hv.z = f2h_bits(zr2, zi2); hv.w = f2h_bits(zr3, zi3);
      *reinterpret_cast<int4*>(Yh + (size_t)wid * 16 + 4 * fq) = hv;
    }
  }
}

// ---------------- layer-2 dense: U2h = t1'@W2[2] (fp16) ; D = X2@(W2[0]-W2[2]) + t1'@W2[1] + b2
__global__ __launch_bounds__(256) void k_d2(const float* __restrict__ X2, const float* __restrict__ T1,
                                            const float* __restrict__ W2g, const float* __restrict__ b2g,
                                            __half2* __restrict__ U2h, float* __restrict__ D, int n) {
  __shared__ float sm[1040];
  int tid = threadIdx.x;
  for (int t = tid; t < 768; t += 256) sm[t] = W2g[t];
  if (tid < 16) sm[768 + tid] = b2g[tid];
  __syncthreads();
  if (tid < 256) sm[784 + tid] = sm[tid] - sm[512 + tid];
  __syncthreads();
  int i = blockIdx.x * 256 + tid;
  if (i >= n) return;
  float re[16], im[16], tr[16], ti[16];
  #pragma unroll
  for (int k = 0; k < 16; ++k) {
    float2 a = *reinterpret_cast<const float2*>(X2 + i * 32 + 2 * k);
    re[k] = a.x; im[k] = a.y;
    float2 b = *reinterpret_cast<const float2*>(T1 + i * 32 + 2 * k);
    tr[k] = b.x; ti[k] = b.y;
  }
  #pragma unroll
  for (int f = 0; f < 16; ++f) {
    float ur = 0.f, ui = 0.f;
    float dr = sm[768 + f], di = sm[768 + f];
    #pragma unroll
    for (int k = 0; k < 16; ++k) {
      float w2 = sm[512 + k * 16 + f];
      float w1 = sm[256 + k * 16 + f];
      float w02 = sm[784 + k * 16 + f];
      ur = fmaf(tr[k], w2, ur);
      ui = fmaf(ti[k], w2, ui);
      dr = fmaf(re[k], w02, dr); dr = fmaf(tr[k], w1, dr);
      di = fmaf(im[k], w02, di); di = fmaf(ti[k], w1, di);
    }
    U2h[(size_t)i * 16 + f] = __floats2half2_rn(ur, ui);
    *reinterpret_cast<float2*>(D + i * 32 + 2 * f) = make_float2(dr, di);
  }
}

extern "C" void kernel_launch(void* const* d_in, const int* in_sizes, int n_in,
                              void* d_out, int out_size, void* d_ws, size_t ws_size,
                              hipStream_t stream) {
  const int* x = (const int*)d_in[0];
  const int* ei = (const int*)d_in[1];
  const float* ew = (const float*)d_in[2];
  const float* btab = (const float*)d_in[3];
  const float* gtab = (const float*)d_in[4];
  const float* stab = (const float*)d_in[5];
  const float* W1 = (const float*)d_in[6];
  const float* b1 = (const float*)d_in[7];
  const float* W2 = (const float*)d_in[8];
  const float* b2 = (const float*)d_in[9];
  const float* Wc = (const float*)d_in[10];
  const float* bc = (const float*)d_in[11];
  const float* Wl = (const float*)d_in[12];
  const float* bl = (const float*)d_in[13];
  float* yout = (float*)d_out;

  const int N_ = in_sizes[0] / 20;
  const int E_ = in_sizes[1] / 2;
  const int M_ = 2 * E_;
  const int rng = (N_ + NRANGE - 1) / NRANGE;  // nodes per range (<= MAXRNG)

  size_t off = 0;
  auto take = [&](size_t bytes) -> void* {
    void* p = (char*)d_ws + off;
    off += (bytes + 255) & ~(size_t)255;
    return p;
  };
  float* PQ   = (float*)take((size_t)N_ * 32 * 4);  // f32 pairs [p,q]; overlay: Hg
  float* o0   = (float*)take((size_t)N_ * 16 * 4);
  float* Ubuf = (float*)take((size_t)N_ * 32 * 4);  // f32 dense (hop_full<0> out, k_d2 in)
  float* ABuf = (float*)take((size_t)N_ * 32 * 4);  // AB then D
  float* X2   = (float*)take((size_t)N_ * 32 * 4);  // f32 X2 for k_d2
  float* dinv = (float*)take((size_t)N_ * 4);
  int* cnt    = (int*)take((size_t)N_ * 4);
  int* rowp   = (int*)take((size_t)(N_ + 1) * 4);
  int* bsum   = (int*)take(1024 * 4);
  float* weff = (float*)take(64 * 4);
  int* rcnt   = (int*)take(NKEY * 4);
  int* rbase  = (int*)take((NKEY + 1) * 4);
  int* rcur   = (int*)take(NKEY * 4);
  int* brow   = (int*)take((size_t)M_ * 4);   // overlay after place2: PQh + Uh
  int2* bsw   = (int2*)take((size_t)M_ * 8);  // overlay after place2: X2h + U2h
  int2* recs  = (int2*)take((size_t)M_ * 8);
  (void)ws_size; (void)n_in; (void)out_size;

  int* Hg      = (int*)PQ;
  __half2* PQh = (__half2*)brow;
  __half2* Uh  = (__half2*)((char*)brow + (size_t)N_ * 64);
  __half2* X2h = (__half2*)bsw;
  __half2* U2h = (__half2*)((char*)bsw + (size_t)N_ * 64);

  int nbN = (N_ + 255) / 256;
  int nbS = (N_ + 1023) / 1024;
  int nbH = (N_ + 3) / 4;      // one wave per node
  int nbT = (N_ + 511) / 512;
  int nbB = (E_ + 1023) / 1024;

  hipMemsetAsync(rcnt, 0, NKEY * 4, stream);

  k_weff<<<1, 64, 0, stream>>>(Wc, bc, Wl, bl, weff);

  // ---- CSR build: (range, src-group) bucket sort -> rows emerge src-sorted
  k_rhist<<<512, 256, 0, stream>>>(ei, rcnt, rng, E_);
  k_rbase<<<1, 64, 0, stream>>>(rcnt, rbase, rcur);
  k_bucket<<<nbB, 256, 0, stream>>>(ei, ew, rcur, brow, bsw, rng, E_);
  k_hist2<<<NRANGE * NS2, 1024, 0, stream>>>(brow, rbase, Hg, rng);
  k_scanH<<<nbT, 512, 0, stream>>>(Hg, cnt, rng, N_);
  k_scan_a<<<nbS, 1024, 0, stream>>>(cnt, rowp, bsum, N_);
  k_scan_b<<<1, 128, 0, stream>>>(bsum, nbS, rowp, N_);
  k_scan_c<<<nbS, 1024, 0, stream>>>(rowp, bsum, N_);
  k_place2<<<NRANGE * NS2, 1024, 0, stream>>>(brow, bsw, rbase, rowp, Hg, recs, rng);

  // ---- node-wise prep (after build so all overlays are dead)
  k_embed<<<nbN, 256, 0, stream>>>(x, btab, gtab, stab, W1, b1, PQ, PQh, o0, N_);
  k_rowdeg<<<nbH, 256, 0, stream>>>(rowp, recs, dinv, N_);
  k_norm<<<nbH, 256, 0, stream>>>(rowp, recs, dinv, N_);

  // layer 1
  k_hop_sym<<<nbH, 256, 0, stream>>>(rowp, recs, PQh, Uh, ABuf, N_);
  k_hop_full<1><<<nbH, 256, 0, stream>>>(rowp, recs, Uh, X2, X2h, o0, ABuf, PQ,
                                         nullptr, nullptr, N_);
  // layer 2
  k_hop_full<0><<<nbH, 256, 0, stream>>>(rowp, recs, X2h, Ubuf, nullptr, nullptr,
                                         nullptr, nullptr, nullptr, nullptr, N_);
  k_d2<<<nbN, 256, 0, stream>>>(X2, Ubuf, W2, b2, U2h, ABuf, N_);
  k_hop_full<2><<<nbH, 256, 0, stream>>>(rowp, recs, U2h, yout, nullptr, nullptr,
                                         nullptr, nullptr, ABuf, weff, N_);
}

// Round 11
// 452.167 us; speedup vs baseline: 1.1945x; 1.1945x over previous
//
#include <hip/hip_runtime.h>
#include <hip/hip_fp16.h>
#include <math.h>

static constexpr float PI2Q = 1.57079632679489662f; // 2*pi*Q, Q=0.25
#define CSH 9
#define CROWS 512     // rows per chunk; one block owns one chunk's recs span
#define MAXKEY 256    // max chunks (N <= 131072)

__device__ __forceinline__ float2 h2f_bits(int b) {
  __half2 h = *reinterpret_cast<__half2*>(&b);
  return __half22float2(h);
}
__device__ __forceinline__ int f2h_bits(float a, float b) {
  __half2 h = __floats2half2_rn(a, b);
  return *reinterpret_cast<int*>(&h);
}

// ---------------- head folding: w_eff[k] = sum_j Wc[j,k]*Wl[j]; w_eff[32] = bc@Wl + bl
__global__ void k_weff(const float* __restrict__ Wc, const float* __restrict__ bc,
                       const float* __restrict__ Wl, const float* __restrict__ bl,
                       float* __restrict__ weff) {
  int k = threadIdx.x;
  if (k < 32) {
    float s = 0.f;
    #pragma unroll
    for (int j = 0; j < 32; ++j) s += Wc[j * 32 + k] * Wl[j];
    weff[k] = s;
  } else if (k == 32) {
    float s = 0.f;
    for (int j = 0; j < 32; ++j) s += bc[j] * Wl[j];
    weff[32] = s + bl[0];
  }
}

// ---------------- embedding + layer-1 dense premultiplies (f32 PQ + fp16 PQh)
__global__ __launch_bounds__(256) void k_embed(
    const int* __restrict__ x, const float* __restrict__ btab,
    const float* __restrict__ gtab, const float* __restrict__ stab,
    const float* __restrict__ W1, const float* __restrict__ b1,
    float* __restrict__ PQ, __half2* __restrict__ PQh, float* __restrict__ o0, int n) {
  __shared__ float sm[3184];
  int tid = threadIdx.x;
  for (int t = tid; t < 1536; t += 256) sm[t] = W1[t];
  if (tid < 16) sm[1536 + tid] = b1[tid];
  for (int t = tid; t < 128; t += 256) sm[1552 + t] = btab[t];
  for (int t = tid; t < 64; t += 256) sm[1680 + t] = gtab[t];
  for (int t = tid; t < 1440; t += 256) sm[1744 + t] = stab[t];
  __syncthreads();
  int i = blockIdx.x * 256 + tid;
  if (i >= n) return;
  int xr[20];
  #pragma unroll
  for (int j = 0; j < 20; ++j) xr[j] = x[i * 20 + j];
  int bi = 0;
  #pragma unroll
  for (int j = 3; j >= 0; --j) if (xr[j] == 1) bi = j;
  int g = xr[4];
  float h[32];
  #pragma unroll
  for (int f = 0; f < 32; ++f) {
    float s = 0.f;
    #pragma unroll
    for (int j = 0; j < 15; ++j) s += sm[1744 + j * 96 + xr[5 + j] * 32 + f];
    h[f] = (sm[1552 + bi * 32 + f] + sm[1680 + g * 32 + f] + s * (1.f / 15.f)) * (1.f / 3.f);
  }
  #pragma unroll
  for (int f = 0; f < 16; ++f) {
    float o = sm[1536 + f], p = 0.f, q = 0.f;
    #pragma unroll
    for (int k = 0; k < 32; ++k) {
      float hk = h[k];
      o = fmaf(hk, sm[k * 16 + f], o);
      p = fmaf(hk, sm[512 + k * 16 + f], p);
      q = fmaf(hk, sm[1024 + k * 16 + f], q);
    }
    o0[i * 16 + f] = o;
    PQ[i * 32 + 2 * f] = p;
    PQ[i * 32 + 2 * f + 1] = q;
    PQh[(size_t)i * 16 + f] = __floats2half2_rn(p, q);
  }
}

// ---------------- chunk histogram over edge list: key = row >> CSH
__global__ __launch_bounds__(256) void k_rhist(const int* __restrict__ ei, int* __restrict__ rcnt,
                                               int E_) {
  __shared__ int h[MAXKEY * 8];
  int tid = threadIdx.x;
  for (int t = tid; t < MAXKEY * 8; t += 256) h[t] = 0;
  __syncthreads();
  int slot = tid & 7;
  int stride = gridDim.x * 256;
  for (int e = blockIdx.x * 256 + tid; e < E_; e += stride) {
    int s = ei[e], d = ei[E_ + e];
    atomicAdd(&h[(d >> CSH) * 8 + slot], 1);
    atomicAdd(&h[(s >> CSH) * 8 + slot], 1);
  }
  __syncthreads();
  for (int t = tid; t < MAXKEY; t += 256) {
    int sum = 0;
    #pragma unroll
    for (int j = 0; j < 8; ++j) sum += h[t * 8 + j];
    if (sum) atomicAdd(&rcnt[t], sum);
  }
}

// ---------------- chunk bases + cursors (rbase IS the recs chunk base: rows globally ordered)
__global__ void k_rbase(const int* __restrict__ rcnt, int* __restrict__ rbase, int* __restrict__ rcur,
                        int nkey) {
  if (threadIdx.x == 0) {
    int run = 0;
    for (int r = 0; r < nkey; ++r) { rbase[r] = run; rcur[r] = run; run += rcnt[r]; }
    rbase[nkey] = run;
  }
}

// ---------------- bucket stubs by chunk (block-level reservation, 2048 edges/block)
__global__ __launch_bounds__(256) void k_bucket(const int* __restrict__ ei, const float* __restrict__ ew,
                                                int* __restrict__ rcur, int* __restrict__ brow,
                                                int2* __restrict__ bsw, int E_) {
  __shared__ int lcnt[MAXKEY];
  __shared__ int gbase[MAXKEY];
  int tid = threadIdx.x;
  lcnt[tid] = 0;
  __syncthreads();
  int e0 = blockIdx.x * 2048;
  int s[8], d[8], wb[8], kA[8], kB[8], la[8], lb[8];
  #pragma unroll
  for (int j = 0; j < 8; ++j) {
    int e = e0 + j * 256 + tid;
    if (e < E_) {
      s[j] = ei[e]; d[j] = ei[E_ + e]; wb[j] = __float_as_int(ew[e]);
      kA[j] = d[j] >> CSH;
      kB[j] = s[j] >> CSH;
      la[j] = atomicAdd(&lcnt[kA[j]], 1);
      lb[j] = atomicAdd(&lcnt[kB[j]], 1);
    } else {
      kA[j] = -1; kB[j] = -1; s[j] = 0; d[j] = 0; wb[j] = 0; la[j] = 0; lb[j] = 0;
    }
  }
  __syncthreads();
  gbase[tid] = lcnt[tid] ? atomicAdd(&rcur[tid], lcnt[tid]) : 0;
  __syncthreads();
  #pragma unroll
  for (int j = 0; j < 8; ++j) {
    if (kA[j] >= 0) {
      int pA = gbase[kA[j]] + la[j];
      brow[pA] = d[j];
      bsw[pA] = make_int2(s[j], wb[j]);                    // theta = +
      int pB = gbase[kB[j]] + lb[j];
      brow[pB] = s[j];
      bsw[pB] = make_int2(d[j] | (int)0x80000000, wb[j]);  // theta = -
    }
  }
}

// ---------------- per-chunk: row hist + weighted degree + local prefix -> rowp, dinv
__global__ __launch_bounds__(1024) void k_chunkdeg(const int* __restrict__ brow, const int2* __restrict__ bsw,
                                                   const int* __restrict__ rbase, int* __restrict__ rowp,
                                                   float* __restrict__ dinv, int n, int nkey) {
  __shared__ int hist[CROWS];
  __shared__ float wsum[CROWS];
  __shared__ int pref[CROWS];
  int c = blockIdx.x;
  int base = c << CSH;
  int rows = min(CROWS, n - base);
  int tid = threadIdx.x;
  if (tid < CROWS) { hist[tid] = 0; wsum[tid] = 0.f; }
  __syncthreads();
  int k0 = rbase[c], k1 = rbase[c + 1];
  for (int k = k0 + tid; k < k1; k += 1024) {
    int rl = brow[k] - base;
    atomicAdd(&hist[rl], 1);
    atomicAdd(&wsum[rl], __int_as_float(bsw[k].y));
  }
  __syncthreads();
  if (tid < CROWS) pref[tid] = hist[tid];
  __syncthreads();
  for (int off = 1; off < CROWS; off <<= 1) {
    int t = (tid < CROWS && tid >= off) ? pref[tid - off] : 0;
    __syncthreads();
    if (tid < CROWS) pref[tid] += t;
    __syncthreads();
  }
  if (tid < rows) {
    rowp[base + tid] = k0 + pref[tid] - hist[tid];  // exclusive prefix + chunk base
    float dg = 0.5f * wsum[tid];
    dinv[base + tid] = (dg > 0.f) ? rsqrtf(dg) : 0.f;
  }
  if (c == 0 && tid == 0) rowp[n] = rbase[nkey];
}

// ---------------- per-chunk placement + fused normalization (single exclusive writer per recs line)
__global__ __launch_bounds__(1024) void k_chunkplace(const int* __restrict__ brow, const int2* __restrict__ bsw,
                                                     const int* __restrict__ rbase, const int* __restrict__ rowp,
                                                     const float* __restrict__ dinv, int2* __restrict__ recs,
                                                     int n) {
  __shared__ int cur[CROWS];
  __shared__ float dloc[CROWS];
  int c = blockIdx.x;
  int base = c << CSH;
  int rows = min(CROWS, n - base);
  int tid = threadIdx.x;
  if (tid < rows) { cur[tid] = rowp[base + tid]; dloc[tid] = dinv[base + tid]; }
  __syncthreads();
  int k0 = rbase[c], k1 = rbase[c + 1];
  for (int k = k0 + tid; k < k1; k += 1024) {
    int rl = brow[k] - base;
    int2 p = bsw[k];
    int s = p.x & 0x7fffffff;
    float w = __int_as_float(p.y);
    float nrm = dloc[rl] * 0.5f * w * dinv[s];
    float sn, cs;
    sincosf(PI2Q * w, &sn, &cs);
    float ar = -nrm * cs;
    float ai = (p.x < 0) ? nrm * sn : -nrm * sn;
    int pos = atomicAdd(&cur[rl], 1);
    recs[pos] = make_int2(p.x, f2h_bits(ar, ai));  // dir bit kept in .x; hops mask it
  }
}

// ---------------- layer-1 hop 1 (xr==xi symmetry): stub-quad layout (16 stubs x 4 lanes)
__global__ __launch_bounds__(256, 8) void k_hop_sym(
    const int* __restrict__ rowp, const int2* __restrict__ recs,
    const __half2* __restrict__ PQh, __half2* __restrict__ Uh, float* __restrict__ AB, int n) {
  int wid = (blockIdx.x * 256 + threadIdx.x) >> 6;
  if (wid >= n) return;
  int lane = threadIdx.x & 63;
  int fq = lane & 3, su = lane >> 2;
  int rs = rowp[wid], rend = rowp[wid + 1];
  float aA[4] = {0.f, 0.f, 0.f, 0.f}, aB[4] = {0.f, 0.f, 0.f, 0.f};
  float aC[4] = {0.f, 0.f, 0.f, 0.f}, aD[4] = {0.f, 0.f, 0.f, 0.f};
  const long long* rq = reinterpret_cast<const long long*>(recs);
  const int4* Pq = reinterpret_cast<const int4*>(PQh);
  for (int k = rs + su; k < rend; k += 16) {
    long long r0 = __builtin_nontemporal_load(rq + k);
    int s = ((int)r0) & 0x7fffffff;
    float2 a = h2f_bits((int)(r0 >> 32));
    float wm = a.x - a.y, wp = a.x + a.y;
    int4 v = Pq[(size_t)s * 4 + fq];
    float2 x0 = h2f_bits(v.x), x1 = h2f_bits(v.y), x2 = h2f_bits(v.z), x3 = h2f_bits(v.w);
    aA[0] = fmaf(wm, x0.x, aA[0]); aB[0] = fmaf(wp, x0.x, aB[0]);
    aC[0] = fmaf(wm, x0.y, aC[0]); aD[0] = fmaf(wp, x0.y, aD[0]);
    aA[1] = fmaf(wm, x1.x, aA[1]); aB[1] = fmaf(wp, x1.x, aB[1]);
    aC[1] = fmaf(wm, x1.y, aC[1]); aD[1] = fmaf(wp, x1.y, aD[1]);
    aA[2] = fmaf(wm, x2.x, aA[2]); aB[2] = fmaf(wp, x2.x, aB[2]);
    aC[2] = fmaf(wm, x2.y, aC[2]); aD[2] = fmaf(wp, x2.y, aD[2]);
    aA[3] = fmaf(wm, x3.x, aA[3]); aB[3] = fmaf(wp, x3.x, aB[3]);
    aC[3] = fmaf(wm, x3.y, aC[3]); aD[3] = fmaf(wp, x3.y, aD[3]);
  }
  #pragma unroll
  for (int j = 0; j < 4; ++j) {
    aA[j] += __shfl_xor(aA[j], 4); aA[j] += __shfl_xor(aA[j], 8);
    aA[j] += __shfl_xor(aA[j], 16); aA[j] += __shfl_xor(aA[j], 32);
    aB[j] += __shfl_xor(aB[j], 4); aB[j] += __shfl_xor(aB[j], 8);
    aB[j] += __shfl_xor(aB[j], 16); aB[j] += __shfl_xor(aB[j], 32);
    aC[j] += __shfl_xor(aC[j], 4); aC[j] += __shfl_xor(aC[j], 8);
    aC[j] += __shfl_xor(aC[j], 16); aC[j] += __shfl_xor(aC[j], 32);
    aD[j] += __shfl_xor(aD[j], 4); aD[j] += __shfl_xor(aD[j], 8);
    aD[j] += __shfl_xor(aD[j], 16); aD[j] += __shfl_xor(aD[j], 32);
  }
  if (lane < 4) {
    *reinterpret_cast<float4*>(AB + wid * 32 + 8 * fq) = make_float4(aA[0], aB[0], aA[1], aB[1]);
    *reinterpret_cast<float4*>(AB + wid * 32 + 8 * fq + 4) = make_float4(aA[2], aB[2], aA[3], aB[3]);
    int4 hv;
    hv.x = f2h_bits(aC[0], aD[0]); hv.y = f2h_bits(aC[1], aD[1]);
    hv.z = f2h_bits(aC[2], aD[2]); hv.w = f2h_bits(aC[3], aD[3]);
    *reinterpret_cast<int4*>(Uh + (size_t)wid * 16 + 4 * fq) = hv;
  }
}

// ---------------- full complex hop, stub-quad layout. MODE 0: f32 out; 1: layer-1 epilogue; 2: head
template <int MODE>
__global__ __launch_bounds__(256, 8) void k_hop_full(
    const int* __restrict__ rowp, const int2* __restrict__ recs,
    const __half2* __restrict__ Xh, float* __restrict__ Y, __half2* __restrict__ Yh,
    const float* __restrict__ o0, const float* __restrict__ AB, const float* __restrict__ PQ,
    const float* __restrict__ D, const float* __restrict__ weff, int n) {
  int wid = (blockIdx.x * 256 + threadIdx.x) >> 6;
  if (wid >= n) return;
  int lane = threadIdx.x & 63;
  int fq = lane & 3, su = lane >> 2;
  int rs = rowp[wid], rend = rowp[wid + 1];
  float aR[4] = {0.f, 0.f, 0.f, 0.f}, aI[4] = {0.f, 0.f, 0.f, 0.f};
  const long long* rq = reinterpret_cast<const long long*>(recs);
  const int4* Xq = reinterpret_cast<const int4*>(Xh);
  for (int k = rs + su; k < rend; k += 16) {
    long long r0 = __builtin_nontemporal_load(rq + k);
    int s = ((int)r0) & 0x7fffffff;
    float2 a = h2f_bits((int)(r0 >> 32));
    int4 v = Xq[(size_t)s * 4 + fq];
    float2 x0 = h2f_bits(v.x), x1 = h2f_bits(v.y), x2 = h2f_bits(v.z), x3 = h2f_bits(v.w);
    aR[0] = fmaf(a.x, x0.x, aR[0]); aR[0] = fmaf(-a.y, x0.y, aR[0]);
    aI[0] = fmaf(a.x, x0.y, aI[0]); aI[0] = fmaf(a.y, x0.x, aI[0]);
    aR[1] = fmaf(a.x, x1.x, aR[1]); aR[1] = fmaf(-a.y, x1.y, aR[1]);
    aI[1] = fmaf(a.x, x1.y, aI[1]); aI[1] = fmaf(a.y, x1.x, aI[1]);
    aR[2] = fmaf(a.x, x2.x, aR[2]); aR[2] = fmaf(-a.y, x2.y, aR[2]);
    aI[2] = fmaf(a.x, x2.y, aI[2]); aI[2] = fmaf(a.y, x2.x, aI[2]);
    aR[3] = fmaf(a.x, x3.x, aR[3]); aR[3] = fmaf(-a.y, x3.y, aR[3]);
    aI[3] = fmaf(a.x, x3.y, aI[3]); aI[3] = fmaf(a.y, x3.x, aI[3]);
  }
  #pragma unroll
  for (int j = 0; j < 4; ++j) {
    aR[j] += __shfl_xor(aR[j], 4); aR[j] += __shfl_xor(aR[j], 8);
    aR[j] += __shfl_xor(aR[j], 16); aR[j] += __shfl_xor(aR[j], 32);
    aI[j] += __shfl_xor(aI[j], 4); aI[j] += __shfl_xor(aI[j], 8);
    aI[j] += __shfl_xor(aI[j], 16); aI[j] += __shfl_xor(aI[j], 32);
  }
  if (MODE == 2) {
    float c = 0.f;
    if (lane < 4) {
      float4 d0 = *reinterpret_cast<const float4*>(D + wid * 32 + 8 * fq);
      float4 d1 = *reinterpret_cast<const float4*>(D + wid * 32 + 8 * fq + 4);
      float4 w0 = *reinterpret_cast<const float4*>(weff + 4 * fq);
      float4 w1 = *reinterpret_cast<const float4*>(weff + 16 + 4 * fq);
      c  = (d0.x + 2.f * aR[0]) * w0.x + (d0.y + 2.f * aI[0]) * w1.x;
      c += (d0.z + 2.f * aR[1]) * w0.y + (d0.w + 2.f * aI[1]) * w1.y;
      c += (d1.x + 2.f * aR[2]) * w0.z + (d1.y + 2.f * aI[2]) * w1.z;
      c += (d1.z + 2.f * aR[3]) * w0.w + (d1.w + 2.f * aI[3]) * w1.w;
    }
    c += __shfl_xor(c, 1); c += __shfl_xor(c, 2);
    if (lane == 0) Y[wid] = c + weff[32];
  } else if (lane < 4) {
    if (MODE == 0) {
      *reinterpret_cast<float4*>(Y + wid * 32 + 8 * fq) = make_float4(aR[0], aI[0], aR[1], aI[1]);
      *reinterpret_cast<float4*>(Y + wid * 32 + 8 * fq + 4) = make_float4(aR[2], aI[2], aR[3], aI[3]);
    } else {
      float4 o = *reinterpret_cast<const float4*>(o0 + wid * 16 + 4 * fq);
      float4 ab0 = *reinterpret_cast<const float4*>(AB + wid * 32 + 8 * fq);
      float4 ab1 = *reinterpret_cast<const float4*>(AB + wid * 32 + 8 * fq + 4);
      float4 pq0 = *reinterpret_cast<const float4*>(PQ + wid * 32 + 8 * fq);
      float4 pq1 = *reinterpret_cast<const float4*>(PQ + wid * 32 + 8 * fq + 4);
      float zr0 = o.x + ab0.x + 2.f * aR[0] - pq0.y;
      float zi0 = o.x + ab0.y + 2.f * aI[0] - pq0.y;
      float zr1 = o.y + ab0.z + 2.f * aR[1] - pq0.w;
      float zi1 = o.y + ab0.w + 2.f * aI[1] - pq0.w;
      float zr2 = o.z + ab1.x + 2.f * aR[2] - pq1.y;
      float zi2 = o.z + ab1.y + 2.f * aI[2] - pq1.y;
      float zr3 = o.w + ab1.z + 2.f * aR[3] - pq1.w;
      float zi3 = o.w + ab1.w + 2.f * aI[3] - pq1.w;
      *reinterpret_cast<float4*>(Y + wid * 32 + 8 * fq) = make_float4(zr0, zi0, zr1, zi1);
      *reinterpret_cast<float4*>(Y + wid * 32 + 8 * fq + 4) = make_float4(zr2, zi2, zr3, zi3);
      int4 hv;
      hv.x = f2h_bits(zr0, zi0); hv.y = f2h_bits(zr1, zi1);
      hv.z = f2h_bits(zr2, zi2); hv.w = f2h_bits(zr3, zi3);
      *reinterpret_cast<int4*>(Yh + (size_t)wid * 16 + 4 * fq) = hv;
    }
  }
}

// ---------------- layer-2 dense: U2h = t1'@W2[2] (fp16) ; D = X2@(W2[0]-W2[2]) + t1'@W2[1] + b2
__global__ __launch_bounds__(256) void k_d2(const float* __restrict__ X2, const float* __restrict__ T1,
                                            const float* __restrict__ W2g, const float* __restrict__ b2g,
                                            __half2* __restrict__ U2h, float* __restrict__ D, int n) {
  __shared__ float sm[1040];
  int tid = threadIdx.x;
  for (int t = tid; t < 768; t += 256) sm[t] = W2g[t];
  if (tid < 16) sm[768 + tid] = b2g[tid];
  __syncthreads();
  if (tid < 256) sm[784 + tid] = sm[tid] - sm[512 + tid];
  __syncthreads();
  int i = blockIdx.x * 256 + tid;
  if (i >= n) return;
  float re[16], im[16], tr[16], ti[16];
  #pragma unroll
  for (int k = 0; k < 16; ++k) {
    float2 a = *reinterpret_cast<const float2*>(X2 + i * 32 + 2 * k);
    re[k] = a.x; im[k] = a.y;
    float2 b = *reinterpret_cast<const float2*>(T1 + i * 32 + 2 * k);
    tr[k] = b.x; ti[k] = b.y;
  }
  #pragma unroll
  for (int f = 0; f < 16; ++f) {
    float ur = 0.f, ui = 0.f;
    float dr = sm[768 + f], di = sm[768 + f];
    #pragma unroll
    for (int k = 0; k < 16; ++k) {
      float w2 = sm[512 + k * 16 + f];
      float w1 = sm[256 + k * 16 + f];
      float w02 = sm[784 + k * 16 + f];
      ur = fmaf(tr[k], w2, ur);
      ui = fmaf(ti[k], w2, ui);
      dr = fmaf(re[k], w02, dr); dr = fmaf(tr[k], w1, dr);
      di = fmaf(im[k], w02, di); di = fmaf(ti[k], w1, di);
    }
    U2h[(size_t)i * 16 + f] = __floats2half2_rn(ur, ui);
    *reinterpret_cast<float2*>(D + i * 32 + 2 * f) = make_float2(dr, di);
  }
}

extern "C" void kernel_launch(void* const* d_in, const int* in_sizes, int n_in,
                              void* d_out, int out_size, void* d_ws, size_t ws_size,
                              hipStream_t stream) {
  const int* x = (const int*)d_in[0];
  const int* ei = (const int*)d_in[1];
  const float* ew = (const float*)d_in[2];
  const float* btab = (const float*)d_in[3];
  const float* gtab = (const float*)d_in[4];
  const float* stab = (const float*)d_in[5];
  const float* W1 = (const float*)d_in[6];
  const float* b1 = (const float*)d_in[7];
  const float* W2 = (const float*)d_in[8];
  const float* b2 = (const float*)d_in[9];
  const float* Wc = (const float*)d_in[10];
  const float* bc = (const float*)d_in[11];
  const float* Wl = (const float*)d_in[12];
  const float* bl = (const float*)d_in[13];
  float* yout = (float*)d_out;

  const int N_ = in_sizes[0] / 20;
  const int E_ = in_sizes[1] / 2;
  const int M_ = 2 * E_;
  const int nkey = (N_ + CROWS - 1) >> CSH;  // chunks (<= MAXKEY)

  size_t off = 0;
  auto take = [&](size_t bytes) -> void* {
    void* p = (char*)d_ws + off;
    off += (bytes + 255) & ~(size_t)255;
    return p;
  };
  float* PQ   = (float*)take((size_t)N_ * 32 * 4);  // f32 pairs [p,q]
  float* o0   = (float*)take((size_t)N_ * 16 * 4);
  float* Ubuf = (float*)take((size_t)N_ * 32 * 4);  // f32 dense (hop_full<0> out, k_d2 in)
  float* ABuf = (float*)take((size_t)N_ * 32 * 4);  // AB then D
  float* X2   = (float*)take((size_t)N_ * 32 * 4);  // f32 X2 for k_d2
  float* dinv = (float*)take((size_t)N_ * 4);
  int* rowp   = (int*)take((size_t)(N_ + 1) * 4);
  float* weff = (float*)take(64 * 4);
  int* rcnt   = (int*)take(MAXKEY * 4);
  int* rbase  = (int*)take((MAXKEY + 1) * 4);
  int* rcur   = (int*)take(MAXKEY * 4);
  int* brow   = (int*)take((size_t)M_ * 4);   // overlay after chunkplace: PQh + Uh
  int2* bsw   = (int2*)take((size_t)M_ * 8);  // overlay after chunkplace: X2h + U2h
  int2* recs  = (int2*)take((size_t)M_ * 8);
  (void)ws_size; (void)n_in; (void)out_size;

  // Overlays: PQh/Uh on brow, X2h/U2h on bsw — both dead after k_chunkplace;
  // first written by k_embed / hops, which run after the build.
  __half2* PQh = (__half2*)brow;
  __half2* Uh  = (__half2*)((char*)brow + (size_t)N_ * 64);
  __half2* X2h = (__half2*)bsw;
  __half2* U2h = (__half2*)((char*)bsw + (size_t)N_ * 64);

  int nbN = (N_ + 255) / 256;
  int nbH = (N_ + 3) / 4;           // one wave per node
  int nbB = (E_ + 2047) / 2048;

  hipMemsetAsync(rcnt, 0, MAXKEY * 4, stream);

  k_weff<<<1, 64, 0, stream>>>(Wc, bc, Wl, bl, weff);

  // ---- CSR build: chunk-owned counting sort; deg/rowp/norm fused into the chunk passes
  k_rhist<<<512, 256, 0, stream>>>(ei, rcnt, E_);
  k_rbase<<<1, 64, 0, stream>>>(rcnt, rbase, rcur, nkey);
  k_bucket<<<nbB, 256, 0, stream>>>(ei, ew, rcur, brow, bsw, E_);
  k_chunkdeg<<<nkey, 1024, 0, stream>>>(brow, bsw, rbase, rowp, dinv, N_, nkey);
  k_chunkplace<<<nkey, 1024, 0, stream>>>(brow, bsw, rbase, rowp, dinv, recs, N_);

  // ---- node-wise prep (after build so brow/bsw overlays are dead)
  k_embed<<<nbN, 256, 0, stream>>>(x, btab, gtab, stab, W1, b1, PQ, PQh, o0, N_);

  // layer 1
  k_hop_sym<<<nbH, 256, 0, stream>>>(rowp, recs, PQh, Uh, ABuf, N_);
  k_hop_full<1><<<nbH, 256, 0, stream>>>(rowp, recs, Uh, X2, X2h, o0, ABuf, PQ,
                                         nullptr, nullptr, N_);
  // layer 2
  k_hop_full<0><<<nbH, 256, 0, stream>>>(rowp, recs, X2h, Ubuf, nullptr, nullptr,
                                         nullptr, nullptr, nullptr, nullptr, N_);
  k_d2<<<nbN, 256, 0, stream>>>(X2, Ubuf, W2, b2, U2h, ABuf, N_);
  k_hop_full<2><<<nbH, 256, 0, stream>>>(rowp, recs, U2h, yout, nullptr, nullptr,
                                         nullptr, nullptr, ABuf, weff, N_);
}

// Round 12
// 439.451 us; speedup vs baseline: 1.2291x; 1.0289x over previous
//
#include <hip/hip_runtime.h>
#include <hip/hip_fp16.h>
#include <math.h>

static constexpr float PI2Q = 1.57079632679489662f; // 2*pi*Q, Q=0.25
#define CSH 9
#define CROWS 512     // rows per chunk; one block owns one chunk's recs span
#define MAXKEY 256    // max chunks (N <= 131072)

__device__ __forceinline__ float2 h2f_bits(int b) {
  __half2 h = *reinterpret_cast<__half2*>(&b);
  return __half22float2(h);
}
__device__ __forceinline__ int f2h_bits(float a, float b) {
  __half2 h = __floats2half2_rn(a, b);
  return *reinterpret_cast<int*>(&h);
}

// ---------------- head folding: w_eff[k] = sum_j Wc[j,k]*Wl[j]; w_eff[32] = bc@Wl + bl
__global__ void k_weff(const float* __restrict__ Wc, const float* __restrict__ bc,
                       const float* __restrict__ Wl, const float* __restrict__ bl,
                       float* __restrict__ weff) {
  int k = threadIdx.x;
  if (k < 32) {
    float s = 0.f;
    #pragma unroll
    for (int j = 0; j < 32; ++j) s += Wc[j * 32 + k] * Wl[j];
    weff[k] = s;
  } else if (k == 32) {
    float s = 0.f;
    for (int j = 0; j < 32; ++j) s += bc[j] * Wl[j];
    weff[32] = s + bl[0];
  }
}

// ---------------- embedding + layer-1 dense premultiplies (f32 PQ + fp16 PQh)
__global__ __launch_bounds__(256) void k_embed(
    const int* __restrict__ x, const float* __restrict__ btab,
    const float* __restrict__ gtab, const float* __restrict__ stab,
    const float* __restrict__ W1, const float* __restrict__ b1,
    float* __restrict__ PQ, __half2* __restrict__ PQh, float* __restrict__ o0, int n) {
  __shared__ float sm[3184];
  int tid = threadIdx.x;
  for (int t = tid; t < 1536; t += 256) sm[t] = W1[t];
  if (tid < 16) sm[1536 + tid] = b1[tid];
  for (int t = tid; t < 128; t += 256) sm[1552 + t] = btab[t];
  for (int t = tid; t < 64; t += 256) sm[1680 + t] = gtab[t];
  for (int t = tid; t < 1440; t += 256) sm[1744 + t] = stab[t];
  __syncthreads();
  int i = blockIdx.x * 256 + tid;
  if (i >= n) return;
  int xr[20];
  #pragma unroll
  for (int j = 0; j < 20; ++j) xr[j] = x[i * 20 + j];
  int bi = 0;
  #pragma unroll
  for (int j = 3; j >= 0; --j) if (xr[j] == 1) bi = j;
  int g = xr[4];
  float h[32];
  #pragma unroll
  for (int f = 0; f < 32; ++f) {
    float s = 0.f;
    #pragma unroll
    for (int j = 0; j < 15; ++j) s += sm[1744 + j * 96 + xr[5 + j] * 32 + f];
    h[f] = (sm[1552 + bi * 32 + f] + sm[1680 + g * 32 + f] + s * (1.f / 15.f)) * (1.f / 3.f);
  }
  #pragma unroll
  for (int f = 0; f < 16; ++f) {
    float o = sm[1536 + f], p = 0.f, q = 0.f;
    #pragma unroll
    for (int k = 0; k < 32; ++k) {
      float hk = h[k];
      o = fmaf(hk, sm[k * 16 + f], o);
      p = fmaf(hk, sm[512 + k * 16 + f], p);
      q = fmaf(hk, sm[1024 + k * 16 + f], q);
    }
    o0[i * 16 + f] = o;
    PQ[i * 32 + 2 * f] = p;
    PQ[i * 32 + 2 * f + 1] = q;
    PQh[(size_t)i * 16 + f] = __floats2half2_rn(p, q);
  }
}

// ---------------- chunk histogram over edge list: key = row >> CSH
__global__ __launch_bounds__(256) void k_rhist(const int* __restrict__ ei, int* __restrict__ rcnt,
                                               int E_) {
  __shared__ int h[MAXKEY * 8];
  int tid = threadIdx.x;
  for (int t = tid; t < MAXKEY * 8; t += 256) h[t] = 0;
  __syncthreads();
  int slot = tid & 7;
  int stride = gridDim.x * 256;
  for (int e = blockIdx.x * 256 + tid; e < E_; e += stride) {
    int s = ei[e], d = ei[E_ + e];
    atomicAdd(&h[(d >> CSH) * 8 + slot], 1);
    atomicAdd(&h[(s >> CSH) * 8 + slot], 1);
  }
  __syncthreads();
  for (int t = tid; t < MAXKEY; t += 256) {
    int sum = 0;
    #pragma unroll
    for (int j = 0; j < 8; ++j) sum += h[t * 8 + j];
    if (sum) atomicAdd(&rcnt[t], sum);
  }
}

// ---------------- chunk bases + cursors (rbase IS the recs chunk base: rows globally ordered)
__global__ void k_rbase(const int* __restrict__ rcnt, int* __restrict__ rbase, int* __restrict__ rcur,
                        int nkey) {
  if (threadIdx.x == 0) {
    int run = 0;
    for (int r = 0; r < nkey; ++r) { rbase[r] = run; rcur[r] = run; run += rcnt[r]; }
    rbase[nkey] = run;
  }
}

// ---------------- bucket stubs by chunk (block-level reservation, 2048 edges/block)
__global__ __launch_bounds__(256) void k_bucket(const int* __restrict__ ei, const float* __restrict__ ew,
                                                int* __restrict__ rcur, int* __restrict__ brow,
                                                int2* __restrict__ bsw, int E_) {
  __shared__ int lcnt[MAXKEY];
  __shared__ int gbase[MAXKEY];
  int tid = threadIdx.x;
  lcnt[tid] = 0;
  __syncthreads();
  int e0 = blockIdx.x * 2048;
  int s[8], d[8], wb[8], kA[8], kB[8], la[8], lb[8];
  #pragma unroll
  for (int j = 0; j < 8; ++j) {
    int e = e0 + j * 256 + tid;
    if (e < E_) {
      s[j] = ei[e]; d[j] = ei[E_ + e]; wb[j] = __float_as_int(ew[e]);
      kA[j] = d[j] >> CSH;
      kB[j] = s[j] >> CSH;
      la[j] = atomicAdd(&lcnt[kA[j]], 1);
      lb[j] = atomicAdd(&lcnt[kB[j]], 1);
    } else {
      kA[j] = -1; kB[j] = -1; s[j] = 0; d[j] = 0; wb[j] = 0; la[j] = 0; lb[j] = 0;
    }
  }
  __syncthreads();
  gbase[tid] = lcnt[tid] ? atomicAdd(&rcur[tid], lcnt[tid]) : 0;
  __syncthreads();
  #pragma unroll
  for (int j = 0; j < 8; ++j) {
    if (kA[j] >= 0) {
      int pA = gbase[kA[j]] + la[j];
      brow[pA] = d[j];
      bsw[pA] = make_int2(s[j], wb[j]);                    // theta = +
      int pB = gbase[kB[j]] + lb[j];
      brow[pB] = s[j];
      bsw[pB] = make_int2(d[j] | (int)0x80000000, wb[j]);  // theta = -
    }
  }
}

// ---------------- per-chunk: row hist + weighted degree + local prefix -> rowp, dinv
__global__ __launch_bounds__(1024) void k_chunkdeg(const int* __restrict__ brow, const int2* __restrict__ bsw,
                                                   const int* __restrict__ rbase, int* __restrict__ rowp,
                                                   float* __restrict__ dinv, int n, int nkey) {
  __shared__ int hist[CROWS];
  __shared__ float wsum[CROWS];
  __shared__ int pref[CROWS];
  int c = blockIdx.x;
  int base = c << CSH;
  int rows = min(CROWS, n - base);
  int tid = threadIdx.x;
  if (tid < CROWS) { hist[tid] = 0; wsum[tid] = 0.f; }
  __syncthreads();
  int k0 = rbase[c], k1 = rbase[c + 1];
  for (int k = k0 + tid; k < k1; k += 1024) {
    int rl = brow[k] - base;
    atomicAdd(&hist[rl], 1);
    atomicAdd(&wsum[rl], __int_as_float(bsw[k].y));
  }
  __syncthreads();
  if (tid < CROWS) pref[tid] = hist[tid];
  __syncthreads();
  for (int off = 1; off < CROWS; off <<= 1) {
    int t = (tid < CROWS && tid >= off) ? pref[tid - off] : 0;
    __syncthreads();
    if (tid < CROWS) pref[tid] += t;
    __syncthreads();
  }
  if (tid < rows) {
    rowp[base + tid] = k0 + pref[tid] - hist[tid];  // exclusive prefix + chunk base
    float dg = 0.5f * wsum[tid];
    dinv[base + tid] = (dg > 0.f) ? rsqrtf(dg) : 0.f;
  }
  if (c == 0 && tid == 0) rowp[n] = rbase[nkey];
}

// ---------------- per-chunk placement + fused normalization (single exclusive writer per recs line)
__global__ __launch_bounds__(1024) void k_chunkplace(const int* __restrict__ brow, const int2* __restrict__ bsw,
                                                     const int* __restrict__ rbase, const int* __restrict__ rowp,
                                                     const float* __restrict__ dinv, int2* __restrict__ recs,
                                                     int n) {
  __shared__ int cur[CROWS];
  __shared__ float dloc[CROWS];
  int c = blockIdx.x;
  int base = c << CSH;
  int rows = min(CROWS, n - base);
  int tid = threadIdx.x;
  if (tid < rows) { cur[tid] = rowp[base + tid]; dloc[tid] = dinv[base + tid]; }
  __syncthreads();
  int k0 = rbase[c], k1 = rbase[c + 1];
  for (int k = k0 + tid; k < k1; k += 1024) {
    int rl = brow[k] - base;
    int2 p = bsw[k];
    int s = p.x & 0x7fffffff;
    float w = __int_as_float(p.y);
    float nrm = dloc[rl] * 0.5f * w * dinv[s];
    float sn, cs;
    sincosf(PI2Q * w, &sn, &cs);
    float ar = -nrm * cs;
    float ai = (p.x < 0) ? nrm * sn : -nrm * sn;
    int pos = atomicAdd(&cur[rl], 1);
    recs[pos] = make_int2(p.x, f2h_bits(ar, ai));  // dir bit kept in .x; hops mask it
  }
}

// ---------------- layer-1 hop 1 (xr==xi symmetry): stub-quad layout, 2x unrolled (32 gathers in flight)
__global__ __launch_bounds__(256, 8) void k_hop_sym(
    const int* __restrict__ rowp, const int2* __restrict__ recs,
    const __half2* __restrict__ PQh, __half2* __restrict__ Uh, float* __restrict__ AB, int n) {
  int wid = (blockIdx.x * 256 + threadIdx.x) >> 6;
  if (wid >= n) return;
  int lane = threadIdx.x & 63;
  int fq = lane & 3, su = lane >> 2;
  int rs = rowp[wid], rend = rowp[wid + 1];
  float aA[4] = {0.f, 0.f, 0.f, 0.f}, aB[4] = {0.f, 0.f, 0.f, 0.f};
  float aC[4] = {0.f, 0.f, 0.f, 0.f}, aD[4] = {0.f, 0.f, 0.f, 0.f};
  const long long* rq = reinterpret_cast<const long long*>(recs);
  const int4* Pq = reinterpret_cast<const int4*>(PQh);
  int k = rs + su;
  for (; k + 16 < rend; k += 32) {
    long long r0 = __builtin_nontemporal_load(rq + k);
    long long r1 = __builtin_nontemporal_load(rq + k + 16);
    int s0 = ((int)r0) & 0x7fffffff;
    int s1 = ((int)r1) & 0x7fffffff;
    float2 a0 = h2f_bits((int)(r0 >> 32));
    float2 a1 = h2f_bits((int)(r1 >> 32));
    int4 v0 = Pq[(size_t)s0 * 4 + fq];
    int4 v1 = Pq[(size_t)s1 * 4 + fq];
    float wm0 = a0.x - a0.y, wp0 = a0.x + a0.y;
    float wm1 = a1.x - a1.y, wp1 = a1.x + a1.y;
    {
      float2 x0 = h2f_bits(v0.x), x1 = h2f_bits(v0.y), x2 = h2f_bits(v0.z), x3 = h2f_bits(v0.w);
      aA[0] = fmaf(wm0, x0.x, aA[0]); aB[0] = fmaf(wp0, x0.x, aB[0]);
      aC[0] = fmaf(wm0, x0.y, aC[0]); aD[0] = fmaf(wp0, x0.y, aD[0]);
      aA[1] = fmaf(wm0, x1.x, aA[1]); aB[1] = fmaf(wp0, x1.x, aB[1]);
      aC[1] = fmaf(wm0, x1.y, aC[1]); aD[1] = fmaf(wp0, x1.y, aD[1]);
      aA[2] = fmaf(wm0, x2.x, aA[2]); aB[2] = fmaf(wp0, x2.x, aB[2]);
      aC[2] = fmaf(wm0, x2.y, aC[2]); aD[2] = fmaf(wp0, x2.y, aD[2]);
      aA[3] = fmaf(wm0, x3.x, aA[3]); aB[3] = fmaf(wp0, x3.x, aB[3]);
      aC[3] = fmaf(wm0, x3.y, aC[3]); aD[3] = fmaf(wp0, x3.y, aD[3]);
    }
    {
      float2 x0 = h2f_bits(v1.x), x1 = h2f_bits(v1.y), x2 = h2f_bits(v1.z), x3 = h2f_bits(v1.w);
      aA[0] = fmaf(wm1, x0.x, aA[0]); aB[0] = fmaf(wp1, x0.x, aB[0]);
      aC[0] = fmaf(wm1, x0.y, aC[0]); aD[0] = fmaf(wp1, x0.y, aD[0]);
      aA[1] = fmaf(wm1, x1.x, aA[1]); aB[1] = fmaf(wp1, x1.x, aB[1]);
      aC[1] = fmaf(wm1, x1.y, aC[1]); aD[1] = fmaf(wp1, x1.y, aD[1]);
      aA[2] = fmaf(wm1, x2.x, aA[2]); aB[2] = fmaf(wp1, x2.x, aB[2]);
      aC[2] = fmaf(wm1, x2.y, aC[2]); aD[2] = fmaf(wp1, x2.y, aD[2]);
      aA[3] = fmaf(wm1, x3.x, aA[3]); aB[3] = fmaf(wp1, x3.x, aB[3]);
      aC[3] = fmaf(wm1, x3.y, aC[3]); aD[3] = fmaf(wp1, x3.y, aD[3]);
    }
  }
  if (k < rend) {
    long long r0 = __builtin_nontemporal_load(rq + k);
    int s0 = ((int)r0) & 0x7fffffff;
    float2 a0 = h2f_bits((int)(r0 >> 32));
    float wm0 = a0.x - a0.y, wp0 = a0.x + a0.y;
    int4 v0 = Pq[(size_t)s0 * 4 + fq];
    float2 x0 = h2f_bits(v0.x), x1 = h2f_bits(v0.y), x2 = h2f_bits(v0.z), x3 = h2f_bits(v0.w);
    aA[0] = fmaf(wm0, x0.x, aA[0]); aB[0] = fmaf(wp0, x0.x, aB[0]);
    aC[0] = fmaf(wm0, x0.y, aC[0]); aD[0] = fmaf(wp0, x0.y, aD[0]);
    aA[1] = fmaf(wm0, x1.x, aA[1]); aB[1] = fmaf(wp0, x1.x, aB[1]);
    aC[1] = fmaf(wm0, x1.y, aC[1]); aD[1] = fmaf(wp0, x1.y, aD[1]);
    aA[2] = fmaf(wm0, x2.x, aA[2]); aB[2] = fmaf(wp0, x2.x, aB[2]);
    aC[2] = fmaf(wm0, x2.y, aC[2]); aD[2] = fmaf(wp0, x2.y, aD[2]);
    aA[3] = fmaf(wm0, x3.x, aA[3]); aB[3] = fmaf(wp0, x3.x, aB[3]);
    aC[3] = fmaf(wm0, x3.y, aC[3]); aD[3] = fmaf(wp0, x3.y, aD[3]);
  }
  #pragma unroll
  for (int j = 0; j < 4; ++j) {
    aA[j] += __shfl_xor(aA[j], 4); aA[j] += __shfl_xor(aA[j], 8);
    aA[j] += __shfl_xor(aA[j], 16); aA[j] += __shfl_xor(aA[j], 32);
    aB[j] += __shfl_xor(aB[j], 4); aB[j] += __shfl_xor(aB[j], 8);
    aB[j] += __shfl_xor(aB[j], 16); aB[j] += __shfl_xor(aB[j], 32);
    aC[j] += __shfl_xor(aC[j], 4); aC[j] += __shfl_xor(aC[j], 8);
    aC[j] += __shfl_xor(aC[j], 16); aC[j] += __shfl_xor(aC[j], 32);
    aD[j] += __shfl_xor(aD[j], 4); aD[j] += __shfl_xor(aD[j], 8);
    aD[j] += __shfl_xor(aD[j], 16); aD[j] += __shfl_xor(aD[j], 32);
  }
  if (lane < 4) {
    *reinterpret_cast<float4*>(AB + wid * 32 + 8 * fq) = make_float4(aA[0], aB[0], aA[1], aB[1]);
    *reinterpret_cast<float4*>(AB + wid * 32 + 8 * fq + 4) = make_float4(aA[2], aB[2], aA[3], aB[3]);
    int4 hv;
    hv.x = f2h_bits(aC[0], aD[0]); hv.y = f2h_bits(aC[1], aD[1]);
    hv.z = f2h_bits(aC[2], aD[2]); hv.w = f2h_bits(aC[3], aD[3]);
    *reinterpret_cast<int4*>(Uh + (size_t)wid * 16 + 4 * fq) = hv;
  }
}

// ---------------- full complex hop, stub-quad layout, 2x unrolled. MODE 0: f32 out; 1: epilogue; 2: head
template <int MODE>
__global__ __launch_bounds__(256, 8) void k_hop_full(
    const int* __restrict__ rowp, const int2* __restrict__ recs,
    const __half2* __restrict__ Xh, float* __restrict__ Y, __half2* __restrict__ Yh,
    const float* __restrict__ o0, const float* __restrict__ AB, const float* __restrict__ PQ,
    const float* __restrict__ D, const float* __restrict__ weff, int n) {
  int wid = (blockIdx.x * 256 + threadIdx.x) >> 6;
  if (wid >= n) return;
  int lane = threadIdx.x & 63;
  int fq = lane & 3, su = lane >> 2;
  int rs = rowp[wid], rend = rowp[wid + 1];
  float aR[4] = {0.f, 0.f, 0.f, 0.f}, aI[4] = {0.f, 0.f, 0.f, 0.f};
  const long long* rq = reinterpret_cast<const long long*>(recs);
  const int4* Xq = reinterpret_cast<const int4*>(Xh);
  int k = rs + su;
  for (; k + 16 < rend; k += 32) {
    long long r0 = __builtin_nontemporal_load(rq + k);
    long long r1 = __builtin_nontemporal_load(rq + k + 16);
    int s0 = ((int)r0) & 0x7fffffff;
    int s1 = ((int)r1) & 0x7fffffff;
    float2 a0 = h2f_bits((int)(r0 >> 32));
    float2 a1 = h2f_bits((int)(r1 >> 32));
    int4 v0 = Xq[(size_t)s0 * 4 + fq];
    int4 v1 = Xq[(size_t)s1 * 4 + fq];
    {
      float2 x0 = h2f_bits(v0.x), x1 = h2f_bits(v0.y), x2 = h2f_bits(v0.z), x3 = h2f_bits(v0.w);
      aR[0] = fmaf(a0.x, x0.x, aR[0]); aR[0] = fmaf(-a0.y, x0.y, aR[0]);
      aI[0] = fmaf(a0.x, x0.y, aI[0]); aI[0] = fmaf(a0.y, x0.x, aI[0]);
      aR[1] = fmaf(a0.x, x1.x, aR[1]); aR[1] = fmaf(-a0.y, x1.y, aR[1]);
      aI[1] = fmaf(a0.x, x1.y, aI[1]); aI[1] = fmaf(a0.y, x1.x, aI[1]);
      aR[2] = fmaf(a0.x, x2.x, aR[2]); aR[2] = fmaf(-a0.y, x2.y, aR[2]);
      aI[2] = fmaf(a0.x, x2.y, aI[2]); aI[2] = fmaf(a0.y, x2.x, aI[2]);
      aR[3] = fmaf(a0.x, x3.x, aR[3]); aR[3] = fmaf(-a0.y, x3.y, aR[3]);
      aI[3] = fmaf(a0.x, x3.y, aI[3]); aI[3] = fmaf(a0.y, x3.x, aI[3]);
    }
    {
      float2 x0 = h2f_bits(v1.x), x1 = h2f_bits(v1.y), x2 = h2f_bits(v1.z), x3 = h2f_bits(v1.w);
      aR[0] = fmaf(a1.x, x0.x, aR[0]); aR[0] = fmaf(-a1.y, x0.y, aR[0]);
      aI[0] = fmaf(a1.x, x0.y, aI[0]); aI[0] = fmaf(a1.y, x0.x, aI[0]);
      aR[1] = fmaf(a1.x, x1.x, aR[1]); aR[1] = fmaf(-a1.y, x1.y, aR[1]);
      aI[1] = fmaf(a1.x, x1.y, aI[1]); aI[1] = fmaf(a1.y, x1.x, aI[1]);
      aR[2] = fmaf(a1.x, x2.x, aR[2]); aR[2] = fmaf(-a1.y, x2.y, aR[2]);
      aI[2] = fmaf(a1.x, x2.y, aI[2]); aI[2] = fmaf(a1.y, x2.x, aI[2]);
      aR[3] = fmaf(a1.x, x3.x, aR[3]); aR[3] = fmaf(-a1.y, x3.y, aR[3]);
      aI[3] = fmaf(a1.x, x3.y, aI[3]); aI[3] = fmaf(a1.y, x3.x, aI[3]);
    }
  }
  if (k < rend) {
    long long r0 = __builtin_nontemporal_load(rq + k);
    int s0 = ((int)r0) & 0x7fffffff;
    float2 a0 = h2f_bits((int)(r0 >> 32));
    int4 v0 = Xq[(size_t)s0 * 4 + fq];
    float2 x0 = h2f_bits(v0.x), x1 = h2f_bits(v0.y), x2 = h2f_bits(v0.z), x3 = h2f_bits(v0.w);
    aR[0] = fmaf(a0.x, x0.x, aR[0]); aR[0] = fmaf(-a0.y, x0.y, aR[0]);
    aI[0] = fmaf(a0.x, x0.y, aI[0]); aI[0] = fmaf(a0.y, x0.x, aI[0]);
    aR[1] = fmaf(a0.x, x1.x, aR[1]); aR[1] = fmaf(-a0.y, x1.y, aR[1]);
    aI[1] = fmaf(a0.x, x1.y, aI[1]); aI[1] = fmaf(a0.y, x1.x, aI[1]);
    aR[2] = fmaf(a0.x, x2.x, aR[2]); aR[2] = fmaf(-a0.y, x2.y, aR[2]);
    aI[2] = fmaf(a0.x, x2.y, aI[2]); aI[2] = fmaf(a0.y, x2.x, aI[2]);
    aR[3] = fmaf(a0.x, x3.x, aR[3]); aR[3] = fmaf(-a0.y, x3.y, aR[3]);
    aI[3] = fmaf(a0.x, x3.y, aI[3]); aI[3] = fmaf(a0.y, x3.x, aI[3]);
  }
  #pragma unroll
  for (int j = 0; j < 4; ++j) {
    aR[j] += __shfl_xor(aR[j], 4); aR[j] += __shfl_xor(aR[j], 8);
    aR[j] += __shfl_xor(aR[j], 16); aR[j] += __shfl_xor(aR[j], 32);
    aI[j] += __shfl_xor(aI[j], 4); aI[j] += __shfl_xor(aI[j], 8);
    aI[j] += __shfl_xor(aI[j], 16); aI[j] += __shfl_xor(aI[j], 32);
  }
  if (MODE == 2) {
    float c = 0.f;
    if (lane < 4) {
      float4 d0 = *reinterpret_cast<const float4*>(D + wid * 32 + 8 * fq);
      float4 d1 = *reinterpret_cast<const float4*>(D + wid * 32 + 8 * fq + 4);
      float4 w0 = *reinterpret_cast<const float4*>(weff + 4 * fq);
      float4 w1 = *reinterpret_cast<const float4*>(weff + 16 + 4 * fq);
      c  = (d0.x + 2.f * aR[0]) * w0.x + (d0.y + 2.f * aI[0]) * w1.x;
      c += (d0.z + 2.f * aR[1]) * w0.y + (d0.w + 2.f * aI[1]) * w1.y;
      c += (d1.x + 2.f * aR[2]) * w0.z + (d1.y + 2.f * aI[2]) * w1.z;
      c += (d1.z + 2.f * aR[3]) * w0.w + (d1.w + 2.f * aI[3]) * w1.w;
    }
    c += __shfl_xor(c, 1); c += __shfl_xor(c, 2);
    if (lane == 0) Y[wid] = c + weff[32];
  } else if (lane < 4) {
    if (MODE == 0) {
      *reinterpret_cast<float4*>(Y + wid * 32 + 8 * fq) = make_float4(aR[0], aI[0], aR[1], aI[1]);
      *reinterpret_cast<float4*>(Y + wid * 32 + 8 * fq + 4) = make_float4(aR[2], aI[2], aR[3], aI[3]);
    } else {
      float4 o = *reinterpret_cast<const float4*>(o0 + wid * 16 + 4 * fq);
      float4 ab0 = *reinterpret_cast<const float4*>(AB + wid * 32 + 8 * fq);
      float4 ab1 = *reinterpret_cast<const float4*>(AB + wid * 32 + 8 * fq + 4);
      float4 pq0 = *reinterpret_cast<const float4*>(PQ + wid * 32 + 8 * fq);
      float4 pq1 = *reinterpret_cast<const float4*>(PQ + wid * 32 + 8 * fq + 4);
      float zr0 = o.x + ab0.x + 2.f * aR[0] - pq0.y;
      float zi0 = o.x + ab0.y + 2.f * aI[0] - pq0.y;
      float zr1 = o.y + ab0.z + 2.f * aR[1] - pq0.w;
      float zi1 = o.y + ab0.w + 2.f * aI[1] - pq0.w;
      float zr2 = o.z + ab1.x + 2.f * aR[2] - pq1.y;
      float zi2 = o.z + ab1.y + 2.f * aI[2] - pq1.y;
      float zr3 = o.w + ab1.z + 2.f * aR[3] - pq1.w;
      float zi3 = o.w + ab1.w + 2.f * aI[3] - pq1.w;
      *reinterpret_cast<float4*>(Y + wid * 32 + 8 * fq) = make_float4(zr0, zi0, zr1, zi1);
      *reinterpret_cast<float4*>(Y + wid * 32 + 8 * fq + 4) = make_float4(zr2, zi2, zr3, zi3);
      int4 hv;
      hv.x = f2h_bits(zr0, zi0); hv.y = f2h_bits(zr1, zi1);
      hv.z = f2h_bits(zr2, zi2); hv.w = f2h_bits(zr3, zi3);
      *reinterpret_cast<int4*>(Yh + (size_t)wid * 16 + 4 * fq) = hv;
    }
  }
}

// ---------------- layer-2 dense: U2h = t1'@W2[2] (fp16) ; D = X2@(W2[0]-W2[2]) + t1'@W2[1] + b2
__global__ __launch_bounds__(256) void k_d2(const float* __restrict__ X2, const float* __restrict__ T1,
                                            const float* __restrict__ W2g, const float* __restrict__ b2g,
                                            __half2* __restrict__ U2h, float* __restrict__ D, int n) {
  __shared__ float sm[1040];
  int tid = threadIdx.x;
  for (int t = tid; t < 768; t += 256) sm[t] = W2g[t];
  if (tid < 16) sm[768 + tid] = b2g[tid];
  __syncthreads();
  if (tid < 256) sm[784 + tid] = sm[tid] - sm[512 + tid];
  __syncthreads();
  int i = blockIdx.x * 256 + tid;
  if (i >= n) return;
  float re[16], im[16], tr[16], ti[16];
  #pragma unroll
  for (int k = 0; k < 16; ++k) {
    float2 a = *reinterpret_cast<const float2*>(X2 + i * 32 + 2 * k);
    re[k] = a.x; im[k] = a.y;
    float2 b = *reinterpret_cast<const float2*>(T1 + i * 32 + 2 * k);
    tr[k] = b.x; ti[k] = b.y;
  }
  #pragma unroll
  for (int f = 0; f < 16; ++f) {
    float ur = 0.f, ui = 0.f;
    float dr = sm[768 + f], di = sm[768 + f];
    #pragma unroll
    for (int k = 0; k < 16; ++k) {
      float w2 = sm[512 + k * 16 + f];
      float w1 = sm[256 + k * 16 + f];
      float w02 = sm[784 + k * 16 + f];
      ur = fmaf(tr[k], w2, ur);
      ui = fmaf(ti[k], w2, ui);
      dr = fmaf(re[k], w02, dr); dr = fmaf(tr[k], w1, dr);
      di = fmaf(im[k], w02, di); di = fmaf(ti[k], w1, di);
    }
    U2h[(size_t)i * 16 + f] = __floats2half2_rn(ur, ui);
    *reinterpret_cast<float2*>(D + i * 32 + 2 * f) = make_float2(dr, di);
  }
}

extern "C" void kernel_launch(void* const* d_in, const int* in_sizes, int n_in,
                              void* d_out, int out_size, void* d_ws, size_t ws_size,
                              hipStream_t stream) {
  const int* x = (const int*)d_in[0];
  const int* ei = (const int*)d_in[1];
  const float* ew = (const float*)d_in[2];
  const float* btab = (const float*)d_in[3];
  const float* gtab = (const float*)d_in[4];
  const float* stab = (const float*)d_in[5];
  const float* W1 = (const float*)d_in[6];
  const float* b1 = (const float*)d_in[7];
  const float* W2 = (const float*)d_in[8];
  const float* b2 = (const float*)d_in[9];
  const float* Wc = (const float*)d_in[10];
  const float* bc = (const float*)d_in[11];
  const float* Wl = (const float*)d_in[12];
  const float* bl = (const float*)d_in[13];
  float* yout = (float*)d_out;

  const int N_ = in_sizes[0] / 20;
  const int E_ = in_sizes[1] / 2;
  const int M_ = 2 * E_;
  const int nkey = (N_ + CROWS - 1) >> CSH;  // chunks (<= MAXKEY)

  size_t off = 0;
  auto take = [&](size_t bytes) -> void* {
    void* p = (char*)d_ws + off;
    off += (bytes + 255) & ~(size_t)255;
    return p;
  };
  float* PQ   = (float*)take((size_t)N_ * 32 * 4);  // f32 pairs [p,q]
  float* o0   = (float*)take((size_t)N_ * 16 * 4);
  float* Ubuf = (float*)take((size_t)N_ * 32 * 4);  // f32 dense (hop_full<0> out, k_d2 in)
  float* ABuf = (float*)take((size_t)N_ * 32 * 4);  // AB then D
  float* X2   = (float*)take((size_t)N_ * 32 * 4);  // f32 X2 for k_d2
  float* dinv = (float*)take((size_t)N_ * 4);
  int* rowp   = (int*)take((size_t)(N_ + 1) * 4);
  float* weff = (float*)take(64 * 4);
  int* rcnt   = (int*)take(MAXKEY * 4);
  int* rbase  = (int*)take((MAXKEY + 1) * 4);
  int* rcur   = (int*)take(MAXKEY * 4);
  int* brow   = (int*)take((size_t)M_ * 4);   // overlay after chunkplace: PQh + Uh
  int2* bsw   = (int2*)take((size_t)M_ * 8);  // overlay after chunkplace: X2h + U2h
  int2* recs  = (int2*)take((size_t)M_ * 8);
  (void)ws_size; (void)n_in; (void)out_size;

  // Overlays: PQh/Uh on brow, X2h/U2h on bsw — both dead after k_chunkplace;
  // first written by k_embed / hops, which run after the build.
  __half2* PQh = (__half2*)brow;
  __half2* Uh  = (__half2*)((char*)brow + (size_t)N_ * 64);
  __half2* X2h = (__half2*)bsw;
  __half2* U2h = (__half2*)((char*)bsw + (size_t)N_ * 64);

  int nbN = (N_ + 255) / 256;
  int nbH = (N_ + 3) / 4;           // one wave per node
  int nbB = (E_ + 2047) / 2048;

  hipMemsetAsync(rcnt, 0, MAXKEY * 4, stream);

  k_weff<<<1, 64, 0, stream>>>(Wc, bc, Wl, bl, weff);

  // ---- CSR build: chunk-owned counting sort; deg/rowp/norm fused into the chunk passes
  k_rhist<<<512, 256, 0, stream>>>(ei, rcnt, E_);
  k_rbase<<<1, 64, 0, stream>>>(rcnt, rbase, rcur, nkey);
  k_bucket<<<nbB, 256, 0, stream>>>(ei, ew, rcur, brow, bsw, E_);
  k_chunkdeg<<<nkey, 1024, 0, stream>>>(brow, bsw, rbase, rowp, dinv, N_, nkey);
  k_chunkplace<<<nkey, 1024, 0, stream>>>(brow, bsw, rbase, rowp, dinv, recs, N_);

  // ---- node-wise prep (after build so brow/bsw overlays are dead)
  k_embed<<<nbN, 256, 0, stream>>>(x, btab, gtab, stab, W1, b1, PQ, PQh, o0, N_);

  // layer 1
  k_hop_sym<<<nbH, 256, 0, stream>>>(rowp, recs, PQh, Uh, ABuf, N_);
  k_hop_full<1><<<nbH, 256, 0, stream>>>(rowp, recs, Uh, X2, X2h, o0, ABuf, PQ,
                                         nullptr, nullptr, N_);
  // layer 2
  k_hop_full<0><<<nbH, 256, 0, stream>>>(rowp, recs, X2h, Ubuf, nullptr, nullptr,
                                         nullptr, nullptr, nullptr, nullptr, N_);
  k_d2<<<nbN, 256, 0, stream>>>(X2, Ubuf, W2, b2, U2h, ABuf, N_);
  k_hop_full<2><<<nbH, 256, 0, stream>>>(rowp, recs, U2h, yout, nullptr, nullptr,
                                         nullptr, nullptr, ABuf, weff, N_);
}